// Round 7
// baseline (151.983 us; speedup 1.0000x reference)
//
#include <hip/hip_runtime.h>

// ---------------- geometry ----------------
#define NTOK 49      // tokens per window
#define DIMC 128
#define NH   4
#define NWIN 64
#define NBLK 4096    // B_ = BATCH * NW

// ws layout (bytes):
//   wqkv : bf16[4*24*64*8] = 49152 el -> 98304 B @ 0
//   wproj: bf16[4*8*64*8]  = 16384 el -> 32768 B @ 98304
//   bmf  : f32 [64*4*16*256] = 1048576 el -> 4 MB @ 131072
//          fragment-ordered for S^T: frag (it_k, jt_q), lane, r2 ->
//          q = jt*16+(lane&15), k = it*16+((lane>>4)<<2)+r2
#define WPROJ_OFF 98304
#define BMF_OFF   131072

typedef unsigned short u16x8 __attribute__((ext_vector_type(8)));
typedef __bf16        bf16x8 __attribute__((ext_vector_type(8)));
typedef float         f32x4  __attribute__((ext_vector_type(4)));

__device__ __forceinline__ unsigned short f2bf(float f) {
  return __builtin_bit_cast(unsigned short, (__bf16)f);   // hw RNE cvt
}

__device__ __forceinline__ bf16x8 ld_frag(const unsigned short* p) {
  return __builtin_bit_cast(bf16x8, *(const u16x8*)p);
}

__device__ __forceinline__ bf16x8 pack_bf16x8(float4 lo, float4 hi) {
  bf16x8 r;
  r[0] = (__bf16)lo.x; r[1] = (__bf16)lo.y; r[2] = (__bf16)lo.z; r[3] = (__bf16)lo.w;
  r[4] = (__bf16)hi.x; r[5] = (__bf16)hi.y; r[6] = (__bf16)hi.z; r[7] = (__bf16)hi.w;
  return r;
}

#define MFMA(a, b, c) __builtin_amdgcn_mfma_f32_16x16x32_bf16(a, b, c, 0, 0, 0)

// ---------------- prep: pack weights + fragment-ordered mask/bias ----------------
__global__ void prep_kernel(const float* __restrict__ qkv_w,      // [128][384]
                            const float* __restrict__ proj_w,     // [128][128]
                            const float* __restrict__ bias_table, // [169][4]
                            const int*   __restrict__ rel_idx,    // [49*49]
                            const float* __restrict__ mask,       // [64][49][49]
                            unsigned short* __restrict__ wqkv,
                            unsigned short* __restrict__ wproj,
                            float* __restrict__ bmf)
{
  const int tid = blockIdx.x * blockDim.x + threadIdx.x;
  const int nth = gridDim.x * blockDim.x;

  for (int idx = tid; idx < 4*24*64*8; idx += nth) {
    int ii = idx & 7, lane = (idx >> 3) & 63, rest = idx >> 9;
    int ct = rest % 24, kt = rest / 24;
    int k = kt*32 + ((lane >> 4) << 3) + ii;
    int c = ct*16 + (lane & 15);
    wqkv[idx] = f2bf(qkv_w[k*384 + c]);
  }
  for (int idx = tid; idx < 4*8*64*8; idx += nth) {
    int ii = idx & 7, lane = (idx >> 3) & 63, rest = idx >> 9;
    int ct = rest & 7, kt = rest >> 3;
    int k = kt*32 + ((lane >> 4) << 3) + ii;
    int c = ct*16 + (lane & 15);
    wproj[idx] = f2bf(proj_w[k*128 + c]);
  }
  // bmf for S^T orientation: [(((wi*4+h)*16 + it*4+jt)*64 + lane)*4 + r2]
  for (int idx = tid; idx < NWIN*NH*16*256; idx += nth) {
    int r2   = idx & 3;
    int lane = (idx >> 2) & 63;
    int ij   = (idx >> 8) & 15;
    int h    = (idx >> 12) & 3;
    int wi   = idx >> 14;
    int it = ij >> 2, jt = ij & 3;
    int q = jt*16 + (lane & 15);
    int k = it*16 + ((lane >> 4) << 2) + r2;
    float v = -1e30f;
    if (q < NTOK && k < NTOK)
      v = mask[wi*2401 + q*49 + k] + bias_table[rel_idx[q*49 + k]*4 + h];
    bmf[idx] = v;
  }
}

// ---------------- fused window attention: 2 waves/head, 8 waves, 512 thr ----
// LDS slot (u16), SLOT = 6272 (x4 = 50176 B -> 3 blocks/CU = 24 waves):
//   Q[49][36] @0 | K[49][36] @1764 | (slack) | Vt[32][68] @4096
//   P[64][64] swizzled (el ^= (llo&7)<<3) occupies [0,4096) after S^T frag reads
//   xo[<49][36] @2048 (P-hi region, barrier-protected)
// NaN-proofing (proven r4/r6): K/Q rows>=49 read in-slot finite garbage;
//   S^T it==3 structural zero + bmf-baked -1e30 kill all invalid entries;
//   P rows>=49 stored as exact 0.
#define SLOT 6272
__global__ __launch_bounds__(512, 3) void winattn_kernel(
    const float* __restrict__ x,
    const float* __restrict__ qkv_b,
    const float* __restrict__ proj_b,
    const unsigned short* __restrict__ wqkv,
    const unsigned short* __restrict__ wproj,
    const float* __restrict__ bmf,
    float* __restrict__ out)
{
  __shared__ __align__(16) unsigned short smem[4*SLOT];

  const int b    = blockIdx.x;
  const int wi   = b & (NWIN - 1);
  const int tid  = threadIdx.x;
  const int wave = tid >> 6;
  const int h    = wave & 3;    // head
  const int ws   = wave >> 2;   // sub-wave: token-half 0/1
  const int lane = tid & 63;
  const int lhi  = lane >> 4;   // 0..3
  const int llo  = lane & 15;   // 0..15

  unsigned short* slot = smem + h*SLOT;
  unsigned short* Qh  = slot;          // [49][36]
  unsigned short* Kh  = slot + 1764;   // [49][36]
  unsigned short* Vh  = slot + 4096;   // [32][68]
  unsigned short* Pb  = slot;          // [64][64] swizzled
  unsigned short* XOh = slot + 2048;   // [<49][36]

  const f32x4 zv = {0.f, 0.f, 0.f, 0.f};
  const float* xb = x + (size_t)b * (NTOK*DIMC);

  // ---- QKV GEMM: this wave owns token-tiles i = ws*2 + {0,1} ----
  f32x4 acc[6][2];   // j: 0,1=q  2,3=k  4,5=v
  #pragma unroll
  for (int j = 0; j < 6; j++) { acc[j][0] = zv; acc[j][1] = zv; }

  #pragma unroll
  for (int kt = 0; kt < 4; kt++) {
    bf16x8 a[2];
    #pragma unroll
    for (int il = 0; il < 2; il++) {
      int row = (ws*2 + il)*16 + llo;
      float4 lo = make_float4(0.f,0.f,0.f,0.f), hi = lo;
      if (ws == 0 || row < NTOK) {
        const float4* p = (const float4*)(xb + row*DIMC + kt*32 + lhi*8);
        lo = p[0]; hi = p[1];
      }
      a[il] = pack_bf16x8(lo, hi);
    }
    #pragma unroll
    for (int j = 0; j < 6; j++) {
      int ct = (j >> 1)*8 + h*2 + (j & 1);
      bf16x8 bw = ld_frag(wqkv + (((kt*24 + ct)*64 + lane) << 3));
      #pragma unroll
      for (int il = 0; il < 2; il++) acc[j][il] = MFMA(a[il], bw, acc[j][il]);
    }
  }

  float bias[6];
  #pragma unroll
  for (int j = 0; j < 6; j++)
    bias[j] = qkv_b[((j >> 1)*8 + h*2 + (j & 1))*16 + llo];

  const float scale = 0.17677669529663687f;  // 32^-0.5

  // Q epilogue (own token rows, r < 49)
  #pragma unroll
  for (int j = 0; j < 2; j++) {
    int d = j*16 + llo;
    #pragma unroll
    for (int il = 0; il < 2; il++)
      #pragma unroll
      for (int r2 = 0; r2 < 4; r2++) {
        int r = (ws*2 + il)*16 + lhi*4 + r2;
        if (r < NTOK) Qh[r*36 + d] = f2bf((acc[j][il][r2] + bias[j]) * scale);
      }
  }

  // ---- prefetch this wave's 8 bmf float4 (jt = ws*2 + {0,1}) ----
  float4 bmv[8];   // [it][jtl] -> it*2+jtl
  {
    const float4* bmf4 = (const float4*)bmf + (size_t)(wi*4 + h)*16*64 + lane;
    #pragma unroll
    for (int it = 0; it < 4; it++)
      #pragma unroll
      for (int jtl = 0; jtl < 2; jtl++)
        bmv[it*2 + jtl] = bmf4[(it*4 + ws*2 + jtl)*64];
  }

  // K epilogue
  #pragma unroll
  for (int j = 2; j < 4; j++) {
    int d = (j - 2)*16 + llo;
    #pragma unroll
    for (int il = 0; il < 2; il++)
      #pragma unroll
      for (int r2 = 0; r2 < 4; r2++) {
        int r = (ws*2 + il)*16 + lhi*4 + r2;
        if (r < NTOK) Kh[r*36 + d] = f2bf(acc[j][il][r2] + bias[j]);
      }
  }
  // V epilogue -> Vt[d][token], own token range (finite garbage ok in pads)
  #pragma unroll
  for (int j = 4; j < 6; j++) {
    int d = (j - 4)*16 + llo;
    #pragma unroll
    for (int il = 0; il < 2; il++) {
      ushort4 pk;
      pk.x = f2bf(acc[j][il][0] + bias[j]);
      pk.y = f2bf(acc[j][il][1] + bias[j]);
      pk.z = f2bf(acc[j][il][2] + bias[j]);
      pk.w = f2bf(acc[j][il][3] + bias[j]);
      *(ushort4*)(Vh + d*68 + (ws*2 + il)*16 + lhi*4) = pk;
    }
  }

  __syncthreads();   // B1: Q/K/V halves complete

  // ---- S^T = mfma(K-rows, Q-rows): col llo = q, regs = k ----
  f32x4 s[4][2];   // [it_k][jtl]
  #pragma unroll
  for (int it = 0; it < 4; it++) { s[it][0] = zv; s[it][1] = zv; }

  {
    bf16x8 ka[4], qb[2];
    #pragma unroll
    for (int it = 0; it < 4; it++) ka[it] = ld_frag(Kh + (it*16 + llo)*36 + lhi*8);
    #pragma unroll
    for (int jtl = 0; jtl < 2; jtl++)
      qb[jtl] = ld_frag(Qh + ((ws*2 + jtl)*16 + llo)*36 + lhi*8);
    __builtin_amdgcn_s_setprio(1);
    #pragma unroll
    for (int jtl = 0; jtl < 2; jtl++)
      #pragma unroll
      for (int it = 0; it < 4; it++)
        s[it][jtl] = MFMA(ka[it], qb[jtl], s[it][jtl]);
    __builtin_amdgcn_s_setprio(0);
  }

  // fold mask+bias into s (frees bmv before softmax)
  #pragma unroll
  for (int jtl = 0; jtl < 2; jtl++) {
    #pragma unroll
    for (int it = 0; it < 3; it++) {
      float4 t = bmv[it*2 + jtl];
      #pragma unroll
      for (int r2 = 0; r2 < 4; r2++) s[it][jtl][r2] += (&t.x)[r2];
    }
    s[3][jtl][0] += bmv[6 + jtl].x;   // k=48 (lhi==0); other lanes garbage, zeroed below
  }

  // ---- softmax over k (regs + 2 shfl), normalize, pack -> P (swizzled) ----
  #pragma unroll
  for (int jtl = 0; jtl < 2; jtl++) {
    float e[4][4];
    float psum = 0.f;
    #pragma unroll
    for (int it = 0; it < 3; it++)
      #pragma unroll
      for (int r2 = 0; r2 < 4; r2++) {
        float v = __expf(s[it][jtl][r2]);
        e[it][r2] = v;
        psum += v;
      }
    {
      float v = (lhi == 0) ? __expf(s[3][jtl][0]) : 0.f;
      e[3][0] = v; e[3][1] = 0.f; e[3][2] = 0.f; e[3][3] = 0.f;
      psum += v;
    }
    psum += __shfl_xor(psum, 16, 64);
    psum += __shfl_xor(psum, 32, 64);
    float inv = __builtin_amdgcn_rcpf(psum);
    int q = (ws*2 + jtl)*16 + llo;
    #pragma unroll
    for (int it = 0; it < 4; it++) {
      ushort4 pk;
      pk.x = f2bf(e[it][0] * inv);
      pk.y = f2bf(e[it][1] * inv);
      pk.z = f2bf(e[it][2] * inv);
      pk.w = f2bf(e[it][3] * inv);
      int el = (q*64 + it*16 + lhi*4) ^ ((llo & 7) << 3);
      *(ushort4*)(Pb + el) = pk;
    }
  }

  // ---- PV: D[d][q] = mfma(Vt-rows, P-rows); own q-tiles ----
  f32x4 o[2][2];   // [mt_d][jtl_q]
  o[0][0] = zv; o[0][1] = zv; o[1][0] = zv; o[1][1] = zv;

  #pragma unroll
  for (int ks = 0; ks < 2; ks++) {
    bf16x8 va[2], pbf[2];
    #pragma unroll
    for (int mt = 0; mt < 2; mt++)
      va[mt] = ld_frag(Vh + (mt*16 + llo)*68 + ks*32 + lhi*8);
    #pragma unroll
    for (int jtl = 0; jtl < 2; jtl++) {
      int el = (((ws*2 + jtl)*16 + llo)*64 + ks*32 + lhi*8) ^ ((llo & 7) << 3);
      pbf[jtl] = ld_frag(Pb + el);
    }
    __builtin_amdgcn_s_setprio(1);
    #pragma unroll
    for (int jtl = 0; jtl < 2; jtl++)
      #pragma unroll
      for (int mt = 0; mt < 2; mt++)
        o[mt][jtl] = MFMA(va[mt], pbf[jtl], o[mt][jtl]);
    __builtin_amdgcn_s_setprio(0);
  }

  __syncthreads();   // B2: all PV frag reads done before xo overwrites P-hi

  // ---- xo[q][d] packed stores (own q rows < 49) ----
  #pragma unroll
  for (int jtl = 0; jtl < 2; jtl++) {
    int q = (ws*2 + jtl)*16 + llo;
    if (q < NTOK) {
      #pragma unroll
      for (int mt = 0; mt < 2; mt++) {
        ushort4 pk;
        pk.x = f2bf(o[mt][jtl][0]);
        pk.y = f2bf(o[mt][jtl][1]);
        pk.z = f2bf(o[mt][jtl][2]);
        pk.w = f2bf(o[mt][jtl][3]);
        *(ushort4*)(XOh + q*36 + mt*16 + lhi*4) = pk;
      }
    }
  }

  __syncthreads();   // B3: all heads' xo visible

  // ---- proj: out = xo(all heads) @ proj_w + proj_b ; wave -> 16-col tile ----
  {
    f32x4 pacc[4];
    #pragma unroll
    for (int i = 0; i < 4; i++) pacc[i] = zv;

    #pragma unroll
    for (int kt = 0; kt < 4; kt++) {
      bf16x8 a[4];
      #pragma unroll
      for (int i = 0; i < 4; i++)
        a[i] = ld_frag(smem + kt*SLOT + 2048 + (i*16 + llo)*36 + lhi*8);
      bf16x8 bw = ld_frag(wproj + (((kt*8 + wave)*64 + lane) << 3));
      #pragma unroll
      for (int i = 0; i < 4; i++) pacc[i] = MFMA(a[i], bw, pacc[i]);
    }

    float* op = out + (size_t)b * (NTOK*DIMC);
    int c = wave*16 + llo;
    float pb = proj_b[c];
    #pragma unroll
    for (int i = 0; i < 4; i++)
      #pragma unroll
      for (int r2 = 0; r2 < 4; r2++) {
        int r = i*16 + lhi*4 + r2;
        if (r < NTOK) op[r*128 + c] = pacc[i][r2] + pb;
      }
  }
}

extern "C" void kernel_launch(void* const* d_in, const int* in_sizes, int n_in,
                              void* d_out, int out_size, void* d_ws, size_t ws_size,
                              hipStream_t stream)
{
  const float* x          = (const float*)d_in[0];
  const float* mask       = (const float*)d_in[1];
  const float* qkv_w      = (const float*)d_in[2];
  const float* qkv_b      = (const float*)d_in[3];
  const float* proj_w     = (const float*)d_in[4];
  const float* proj_b     = (const float*)d_in[5];
  const float* bias_table = (const float*)d_in[6];
  const int*   rel_idx    = (const int*)d_in[7];
  float* out = (float*)d_out;

  unsigned short* wqkv  = (unsigned short*)d_ws;
  unsigned short* wproj = (unsigned short*)((char*)d_ws + WPROJ_OFF);
  float*          bmf   = (float*)((char*)d_ws + BMF_OFF);

  prep_kernel<<<1024, 256, 0, stream>>>(qkv_w, proj_w, bias_table, rel_idx, mask,
                                        wqkv, wproj, bmf);
  winattn_kernel<<<NBLK, 512, 0, stream>>>(x, qkv_b, proj_b, wqkv, wproj, bmf, out);
}

// Round 8
// 104.604 us; speedup vs baseline: 1.4529x; 1.4529x over previous
//
#include <hip/hip_runtime.h>

// ---------------- geometry ----------------
#define NTOK 49      // tokens per window
#define DIMC 128
#define NH   4
#define NWIN 64
#define NBLK 4096    // B_ = BATCH * NW

// ws layout (bytes):
//   wqkv : bf16[4*24*64*8] = 49152 el -> 98304 B @ 0
//   wproj: bf16[4*8*64*8]  = 16384 el -> 32768 B @ 98304
//   bmf  : f32 [64*4*16*256] = 1048576 el -> 4 MB @ 131072
//          fragment-ordered for S^T: frag (it_k, jt_q), lane, r2 ->
//          q = jt*16+(lane&15), k = it*16+((lane>>4)<<2)+r2
#define WPROJ_OFF 98304
#define BMF_OFF   131072

typedef unsigned short u16x8 __attribute__((ext_vector_type(8)));
typedef __bf16        bf16x8 __attribute__((ext_vector_type(8)));
typedef float         f32x4  __attribute__((ext_vector_type(4)));

__device__ __forceinline__ unsigned short f2bf(float f) {
  return __builtin_bit_cast(unsigned short, (__bf16)f);   // hw RNE cvt
}

__device__ __forceinline__ bf16x8 ld_frag(const unsigned short* p) {
  return __builtin_bit_cast(bf16x8, *(const u16x8*)p);
}

#define MFMA(a, b, c) __builtin_amdgcn_mfma_f32_16x16x32_bf16(a, b, c, 0, 0, 0)

// ---------------- prep: pack weights + fragment-ordered mask/bias ----------------
__global__ void prep_kernel(const float* __restrict__ qkv_w,      // [128][384]
                            const float* __restrict__ proj_w,     // [128][128]
                            const float* __restrict__ bias_table, // [169][4]
                            const int*   __restrict__ rel_idx,    // [49*49]
                            const float* __restrict__ mask,       // [64][49][49]
                            unsigned short* __restrict__ wqkv,
                            unsigned short* __restrict__ wproj,
                            float* __restrict__ bmf)
{
  const int tid = blockIdx.x * blockDim.x + threadIdx.x;
  const int nth = gridDim.x * blockDim.x;

  for (int idx = tid; idx < 4*24*64*8; idx += nth) {
    int ii = idx & 7, lane = (idx >> 3) & 63, rest = idx >> 9;
    int ct = rest % 24, kt = rest / 24;
    int k = kt*32 + ((lane >> 4) << 3) + ii;
    int c = ct*16 + (lane & 15);
    wqkv[idx] = f2bf(qkv_w[k*384 + c]);
  }
  for (int idx = tid; idx < 4*8*64*8; idx += nth) {
    int ii = idx & 7, lane = (idx >> 3) & 63, rest = idx >> 9;
    int ct = rest & 7, kt = rest >> 3;
    int k = kt*32 + ((lane >> 4) << 3) + ii;
    int c = ct*16 + (lane & 15);
    wproj[idx] = f2bf(proj_w[k*128 + c]);
  }
  // bmf for S^T orientation: [(((wi*4+h)*16 + it*4+jt)*64 + lane)*4 + r2]
  for (int idx = tid; idx < NWIN*NH*16*256; idx += nth) {
    int r2   = idx & 3;
    int lane = (idx >> 2) & 63;
    int ij   = (idx >> 8) & 15;
    int h    = (idx >> 12) & 3;
    int wi   = idx >> 14;
    int it = ij >> 2, jt = ij & 3;
    int q = jt*16 + (lane & 15);
    int k = it*16 + ((lane >> 4) << 2) + r2;
    float v = -1e30f;
    if (q < NTOK && k < NTOK)
      v = mask[wi*2401 + q*49 + k] + bias_table[rel_idx[q*49 + k]*4 + h];
    bmf[idx] = v;
  }
}

// ---------------- fused window attention (wave == head) ----------------
// LDS u16[25088] = 50176 B -> 3 blocks/CU:
//   head region h*4096 (4096 u16): Q[49][36]@0 | K[49][36]@1764 | slack
//     P[64][64] swizzled (el ^= (llo&7)<<3) aliases whole region (after S^T reads)
//     xo[<49][36]@0 aliases P low (after PV frag reads; in-wave DS order)
//   shared tail @16384 (8704 u16): xs[64][136]  --after B1-->  Vt_h[32][68] @ h*2176
// Cross-wave deps ONLY: xs (B0 write-done, B1 read-done) and xo->proj (B2).
// NaN-proofing (proven r4/r6): garbage K/Q rows>=49 killed by it==3 structural
//   zero + bmf-baked -1e30; P rows q>=49 finite-or-discarded; proj A rows>=49
//   read stale finite P data, discarded at out store.
__global__ __launch_bounds__(256, 3) void winattn_kernel(
    const float* __restrict__ x,
    const float* __restrict__ qkv_b,
    const float* __restrict__ proj_b,
    const unsigned short* __restrict__ wqkv,
    const unsigned short* __restrict__ wproj,
    const float* __restrict__ bmf,
    float* __restrict__ out)
{
  __shared__ __align__(16) unsigned short smem[25088];

  const int b    = blockIdx.x;
  const int wi   = b & (NWIN - 1);
  const int tid  = threadIdx.x;
  const int h    = tid >> 6;    // wave == head
  const int lane = tid & 63;
  const int lhi  = lane >> 4;   // 0..3
  const int llo  = lane & 15;   // 0..15

  unsigned short* reg = smem + h*4096;   // per-head region
  unsigned short* Qh  = reg;             // [49][36]
  unsigned short* Kh  = reg + 1764;      // [49][36]
  unsigned short* Pb  = reg;             // [64][64] swizzled
  unsigned short* XOh = reg;             // [<49][36]
  unsigned short* xs  = smem + 16384;    // [64][136] staging
  unsigned short* Vh  = smem + 16384 + h*2176;  // [32][68] after B1

  const f32x4 zv = {0.f, 0.f, 0.f, 0.f};
  const float* xb = x + (size_t)b * (NTOK*DIMC);

  // ---- stage x -> xs (bf16, coalesced float4, zero-pad rows 49..63) ----
  {
    const float4* xv = (const float4*)xb;
    #pragma unroll
    for (int t = 0; t < 8; t++) {
      int idx = t*256 + tid;            // 2048 float4s
      int n = idx >> 5, c4 = idx & 31;  // row, float4-col
      float4 v = make_float4(0.f, 0.f, 0.f, 0.f);
      if (n < NTOK) v = xv[n*32 + c4];
      ushort4 pk;
      pk.x = f2bf(v.x); pk.y = f2bf(v.y); pk.z = f2bf(v.z); pk.w = f2bf(v.w);
      *(ushort4*)(xs + n*136 + c4*4) = pk;
    }
  }
  __syncthreads();   // B0: xs staged

  // ---- QKV GEMM: A-frags from LDS ----
  f32x4 acc[6][4];   // j: 0,1=q  2,3=k  4,5=v
  #pragma unroll
  for (int j = 0; j < 6; j++)
    #pragma unroll
    for (int i = 0; i < 4; i++) acc[j][i] = zv;

  #pragma unroll
  for (int kt = 0; kt < 4; kt++) {
    bf16x8 a[4];
    #pragma unroll
    for (int i = 0; i < 4; i++)
      a[i] = ld_frag(xs + (i*16 + llo)*136 + kt*32 + lhi*8);
    #pragma unroll
    for (int j = 0; j < 6; j++) {
      int ct = (j >> 1)*8 + h*2 + (j & 1);
      bf16x8 bw = ld_frag(wqkv + (((kt*24 + ct)*64 + lane) << 3));
      #pragma unroll
      for (int i = 0; i < 4; i++) acc[j][i] = MFMA(a[i], bw, acc[j][i]);
    }
  }

  float bias[6];
  #pragma unroll
  for (int j = 0; j < 6; j++)
    bias[j] = qkv_b[((j >> 1)*8 + h*2 + (j & 1))*16 + llo];

  const float scale = 0.17677669529663687f;  // 32^-0.5

  // Q epilogue (rows < 49; own region, no xs alias -> pre-B1 ok)
  #pragma unroll
  for (int j = 0; j < 2; j++) {
    int d = j*16 + llo;
    #pragma unroll
    for (int i = 0; i < 4; i++)
      #pragma unroll
      for (int r2 = 0; r2 < 4; r2++) {
        int r = i*16 + lhi*4 + r2;
        if (r < NTOK) Qh[r*36 + d] = f2bf((acc[j][i][r2] + bias[j]) * scale);
      }
  }
  // K epilogue
  #pragma unroll
  for (int j = 2; j < 4; j++) {
    int d = (j - 2)*16 + llo;
    #pragma unroll
    for (int i = 0; i < 4; i++)
      #pragma unroll
      for (int r2 = 0; r2 < 4; r2++) {
        int r = i*16 + lhi*4 + r2;
        if (r < NTOK) Kh[r*36 + d] = f2bf(acc[j][i][r2] + bias[j]);
      }
  }

  // ---- prefetch bmf (16 float4); barrier-wait + S^T hide the latency ----
  float4 bmv[16];
  {
    const float4* bmf4 = (const float4*)bmf + (size_t)(wi*4 + h)*16*64 + lane;
    #pragma unroll
    for (int t = 0; t < 16; t++) bmv[t] = bmf4[t*64];
  }

  __syncthreads();   // B1: all xs reads done -> Vt may overwrite

  // V epilogue -> Vt[d][token], ALL 64 tokens (rows>=49 exact bias, finite)
  #pragma unroll
  for (int j = 4; j < 6; j++) {
    int d = (j - 4)*16 + llo;
    #pragma unroll
    for (int i = 0; i < 4; i++) {
      ushort4 pk;
      pk.x = f2bf(acc[j][i][0] + bias[j]);
      pk.y = f2bf(acc[j][i][1] + bias[j]);
      pk.z = f2bf(acc[j][i][2] + bias[j]);
      pk.w = f2bf(acc[j][i][3] + bias[j]);
      *(ushort4*)(Vh + d*68 + i*16 + lhi*4) = pk;
    }
  }

  // ---- S^T = mfma(K-rows, Q-rows): col llo = q, regs = k ----
  f32x4 s[4][4];   // [it_k][jt_q]
  #pragma unroll
  for (int it = 0; it < 4; it++)
    #pragma unroll
    for (int jt = 0; jt < 4; jt++) s[it][jt] = zv;

  {
    bf16x8 ka[4], qb[4];
    #pragma unroll
    for (int it = 0; it < 4; it++) ka[it] = ld_frag(Kh + (it*16 + llo)*36 + lhi*8);
    #pragma unroll
    for (int jt = 0; jt < 4; jt++) qb[jt] = ld_frag(Qh + (jt*16 + llo)*36 + lhi*8);
    __builtin_amdgcn_s_setprio(1);
    #pragma unroll
    for (int jt = 0; jt < 4; jt++)
      #pragma unroll
      for (int it = 0; it < 4; it++)
        s[it][jt] = MFMA(ka[it], qb[jt], s[it][jt]);
    __builtin_amdgcn_s_setprio(0);
  }

  // ---- softmax over k (regs + 2 shfl), normalize, pack -> P (swizzled) ----
  // k = it*16 + lhi*4 + r2 ; it==3 -> only (lhi==0,r2==0) i.e. k=48 valid
  #pragma unroll
  for (int jt = 0; jt < 4; jt++) {
    float e[4][4];
    float psum = 0.f;
    #pragma unroll
    for (int it = 0; it < 3; it++) {
      float4 t = bmv[it*4 + jt];
      #pragma unroll
      for (int r2 = 0; r2 < 4; r2++) {
        float v = __expf(s[it][jt][r2] + (&t.x)[r2]);
        e[it][r2] = v;
        psum += v;
      }
    }
    {
      float v = (lhi == 0) ? __expf(s[3][jt][0] + bmv[12 + jt].x) : 0.f;
      e[3][0] = v; e[3][1] = 0.f; e[3][2] = 0.f; e[3][3] = 0.f;
      psum += v;
    }
    psum += __shfl_xor(psum, 16, 64);
    psum += __shfl_xor(psum, 32, 64);
    float inv = __builtin_amdgcn_rcpf(psum);
    int q = jt*16 + llo;
    #pragma unroll
    for (int it = 0; it < 4; it++) {
      ushort4 pk;
      pk.x = f2bf(e[it][0] * inv);
      pk.y = f2bf(e[it][1] * inv);
      pk.z = f2bf(e[it][2] * inv);
      pk.w = f2bf(e[it][3] * inv);
      int el = (q*64 + it*16 + lhi*4) ^ ((llo & 7) << 3);
      *(ushort4*)(Pb + el) = pk;
    }
  }

  // ---- PV: D[d][q] = mfma(Vt-rows, P-rows): col llo = q, regs = d ----
  f32x4 o[2][4];   // [mt_d][nt_q]
  #pragma unroll
  for (int mt = 0; mt < 2; mt++)
    #pragma unroll
    for (int nt = 0; nt < 4; nt++) o[mt][nt] = zv;

  #pragma unroll
  for (int ks = 0; ks < 2; ks++) {
    bf16x8 va[2], pbf[4];
    #pragma unroll
    for (int mt = 0; mt < 2; mt++)
      va[mt] = ld_frag(Vh + (mt*16 + llo)*68 + ks*32 + lhi*8);
    #pragma unroll
    for (int nt = 0; nt < 4; nt++) {
      int el = ((nt*16 + llo)*64 + ks*32 + lhi*8) ^ ((llo & 7) << 3);
      pbf[nt] = ld_frag(Pb + el);
    }
    __builtin_amdgcn_s_setprio(1);
    #pragma unroll
    for (int nt = 0; nt < 4; nt++)
      #pragma unroll
      for (int mt = 0; mt < 2; mt++)
        o[mt][nt] = MFMA(va[mt], pbf[nt], o[mt][nt]);
    __builtin_amdgcn_s_setprio(0);
  }

  // ---- xo[q][d] packed stores (q < 49; aliases P low, in-wave order) ----
  #pragma unroll
  for (int nt = 0; nt < 4; nt++) {
    int q = nt*16 + llo;
    if (q < NTOK) {
      #pragma unroll
      for (int mt = 0; mt < 2; mt++) {
        ushort4 pk;
        pk.x = f2bf(o[mt][nt][0]);
        pk.y = f2bf(o[mt][nt][1]);
        pk.z = f2bf(o[mt][nt][2]);
        pk.w = f2bf(o[mt][nt][3]);
        *(ushort4*)(XOh + q*36 + mt*16 + lhi*4) = pk;
      }
    }
  }

  __syncthreads();   // B2: all heads' xo visible

  // ---- proj: out = xo(all heads) @ proj_w + proj_b ; wave h -> cols [h*32,+32) ----
  {
    f32x4 pacc[2][4];
    #pragma unroll
    for (int j = 0; j < 2; j++)
      #pragma unroll
      for (int i = 0; i < 4; i++) pacc[j][i] = zv;

    #pragma unroll
    for (int kt = 0; kt < 4; kt++) {
      bf16x8 a[4];
      #pragma unroll
      for (int i = 0; i < 4; i++)
        a[i] = ld_frag(smem + kt*4096 + (i*16 + llo)*36 + lhi*8);
      #pragma unroll
      for (int j = 0; j < 2; j++) {
        int ct = h*2 + j;
        bf16x8 bw = ld_frag(wproj + (((kt*8 + ct)*64 + lane) << 3));
        #pragma unroll
        for (int i = 0; i < 4; i++) pacc[j][i] = MFMA(a[i], bw, pacc[j][i]);
      }
    }

    float* op = out + (size_t)b * (NTOK*DIMC);
    #pragma unroll
    for (int j = 0; j < 2; j++) {
      int c = (h*2 + j)*16 + llo;
      float pb = proj_b[c];
      #pragma unroll
      for (int i = 0; i < 4; i++)
        #pragma unroll
        for (int r2 = 0; r2 < 4; r2++) {
          int r = i*16 + lhi*4 + r2;
          if (r < NTOK) op[r*128 + c] = pacc[j][i][r2] + pb;
        }
    }
  }
}

extern "C" void kernel_launch(void* const* d_in, const int* in_sizes, int n_in,
                              void* d_out, int out_size, void* d_ws, size_t ws_size,
                              hipStream_t stream)
{
  const float* x          = (const float*)d_in[0];
  const float* mask       = (const float*)d_in[1];
  const float* qkv_w      = (const float*)d_in[2];
  const float* qkv_b      = (const float*)d_in[3];
  const float* proj_w     = (const float*)d_in[4];
  const float* proj_b     = (const float*)d_in[5];
  const float* bias_table = (const float*)d_in[6];
  const int*   rel_idx    = (const int*)d_in[7];
  float* out = (float*)d_out;

  unsigned short* wqkv  = (unsigned short*)d_ws;
  unsigned short* wproj = (unsigned short*)((char*)d_ws + WPROJ_OFF);
  float*          bmf   = (float*)((char*)d_ws + BMF_OFF);

  prep_kernel<<<1024, 256, 0, stream>>>(qkv_w, proj_w, bias_table, rel_idx, mask,
                                        wqkv, wproj, bmf);
  winattn_kernel<<<NBLK, 256, 0, stream>>>(x, qkv_b, proj_b, wqkv, wproj, bmf, out);
}